// Round 5
// baseline (6248.532 us; speedup 1.0000x reference)
//
#include <hip/hip_runtime.h>
#include <hip/hip_bf16.h>
#include <math.h>

#define NF 50000
#define NFP 50048
#define NV 1024
#define NA 64
#define NSLICE 25
#define SCALE_QK 0.088388347648318447f

// ---------------- ws layout (bytes) ----------------
static const size_t OFF_KH   = 0;                                    // ushort [NFP*128]
static const size_t OFF_KL   = OFF_KH  + (size_t)NFP*128*2;          // ushort [NFP*128]
static const size_t OFF_VTH  = OFF_KL  + (size_t)NFP*128*2;          // ushort [128*NFP] (transposed)
static const size_t OFF_VTL  = OFF_VTH + (size_t)128*NFP*2;          // ushort [128*NFP]
static const size_t OFF_P    = OFF_VTL + (size_t)128*NFP*2;          // bf16  [NV*NFP]
static const size_t OFF_H    = OFF_P   + (size_t)NV*NFP*2;           // float [NV*128]
static const size_t OFF_QH   = OFF_H   + (size_t)NV*128*4;           // ushort[NV*128]
static const size_t OFF_QL   = OFF_QH  + (size_t)NV*128*2;           // ushort[NV*128]
static const size_t OFF_PART = OFF_QL  + (size_t)NV*128*2;           // float [25*NV*128]
static const size_t OFF_ACC  = OFF_PART+ (size_t)NSLICE*NV*128*4;    // float Z,Zl,Yp,Yl [4*1024] + slots[3*1024]
static const size_t OFF_CNT  = OFF_ACC + 28672;                      // float [64]

// ---------------- helpers ----------------
typedef __attribute__((ext_vector_type(8)))  short  short8;
typedef __attribute__((ext_vector_type(16))) float  floatx16;
#define MFMA32 __builtin_amdgcn_mfma_f32_32x32x16_bf16

__device__ __forceinline__ float bflo(unsigned w){ union{unsigned u;float f;}c; c.u=w<<16; return c.f; }
__device__ __forceinline__ float bfhi(unsigned w){ union{unsigned u;float f;}c; c.u=w&0xffff0000u; return c.f; }
__device__ __forceinline__ float ubf(unsigned short h){ union{unsigned u;float f;}c; c.u=((unsigned)h)<<16; return c.f; }
__device__ __forceinline__ unsigned short f2bf(float x){ __hip_bfloat16 b=__float2bfloat16(x); return *(unsigned short*)&b; }
__device__ __forceinline__ float geluf(float x){ return 0.5f*x*(1.0f+erff(x*0.70710678118654752f)); }
__device__ __forceinline__ float sigmf(float x){ return 1.0f/(1.0f+__expf(-x)); }
__device__ __forceinline__ short8 ld8(const unsigned short* p){
  union{uint4 u; short8 s;}c; c.u=*(const uint4*)p; return c.s;
}
__device__ __forceinline__ floatx16 fzero16(){
  floatx16 x;
  #pragma unroll
  for(int i=0;i<16;i++) x[i]=0.f;
  return x;
}

// ---------------- cnt per atom ----------------
__global__ __launch_bounds__(256) void cnt_kern(const int* __restrict__ cm, float* __restrict__ cntf){
  __shared__ int sd[256];
  const int a=blockIdx.x, t=threadIdx.x;
  int s=0;
  for (int i=t;i<NV;i+=256) s+=cm[a*NV+i];
  sd[t]=s; __syncthreads();
  for (int o=128;o>0;o>>=1){ if(t<o) sd[t]+=sd[t+o]; __syncthreads(); }
  if (t==0) cntf[a]=(float)sd[0];
}

// ---------------- K/V projection -> bf16 hi/lo splits ----------------
__global__ __launch_bounds__(256)
void kvproj_kern(const float* __restrict__ fe,
                 const float* __restrict__ Wk, const float* __restrict__ bk,
                 const float* __restrict__ Wv, const float* __restrict__ bv,
                 unsigned short* __restrict__ Kh, unsigned short* __restrict__ Kl,
                 unsigned short* __restrict__ Vth, unsigned short* __restrict__ Vtl){
  __shared__ float As[32][68];
  __shared__ float Bs[32][132];
  const int t=threadIdx.x;
  const int f0=blockIdx.x*64;
  const float* W  = blockIdx.y ? Wv : Wk;
  const float* bb = blockIdx.y ? bv : bk;
  float acc[4][8];
  #pragma unroll
  for(int i=0;i<4;i++){ for(int j=0;j<8;j++) acc[i][j]=0.f; }
  for (int kc=0;kc<128;kc+=32){
    { const int floc=t>>2, koff=(t&3)*8; const int f=f0+floc;
      if (f<NF){
        const float* src=fe+((size_t)f<<7)+kc+koff;
        float4 a=*(const float4*)src, b=*(const float4*)(src+4);
        As[koff+0][floc]=a.x; As[koff+1][floc]=a.y; As[koff+2][floc]=a.z; As[koff+3][floc]=a.w;
        As[koff+4][floc]=b.x; As[koff+5][floc]=b.y; As[koff+6][floc]=b.z; As[koff+7][floc]=b.w;
      } else { for(int i=0;i<8;i++) As[koff+i][floc]=0.f; } }
    { const int kk=t>>3, coff=(t&7)*16;
      const float* src=W+((size_t)(kc+kk)<<7)+coff;
      float4 a=*(const float4*)src, b=*(const float4*)(src+4), c=*(const float4*)(src+8), d=*(const float4*)(src+12);
      Bs[kk][coff+0]=a.x;Bs[kk][coff+1]=a.y;Bs[kk][coff+2]=a.z;Bs[kk][coff+3]=a.w;
      Bs[kk][coff+4]=b.x;Bs[kk][coff+5]=b.y;Bs[kk][coff+6]=b.z;Bs[kk][coff+7]=b.w;
      Bs[kk][coff+8]=c.x;Bs[kk][coff+9]=c.y;Bs[kk][coff+10]=c.z;Bs[kk][coff+11]=c.w;
      Bs[kk][coff+12]=d.x;Bs[kk][coff+13]=d.y;Bs[kk][coff+14]=d.z;Bs[kk][coff+15]=d.w; }
    __syncthreads();
    const int mloc=(t&15)*4, nloc=(t>>4)*8;
    #pragma unroll
    for (int kk=0;kk<32;kk++){
      const float4 a=*(const float4*)&As[kk][mloc];
      const float4 b0=*(const float4*)&Bs[kk][nloc];
      const float4 b1=*(const float4*)&Bs[kk][nloc+4];
      const float am[4]={a.x,a.y,a.z,a.w};
      const float bn[8]={b0.x,b0.y,b0.z,b0.w,b1.x,b1.y,b1.z,b1.w};
      #pragma unroll
      for(int mi=0;mi<4;mi++){
        #pragma unroll
        for(int ni=0;ni<8;ni++) acc[mi][ni]=fmaf(am[mi],bn[ni],acc[mi][ni]);
      }
    }
    __syncthreads();
  }
  const int mloc=(t&15)*4, nloc=(t>>4)*8;
  if (blockIdx.y==0){
    #pragma unroll
    for(int mi=0;mi<4;mi++){
      const int f=f0+mloc+mi;
      unsigned short hi[8], lo[8];
      #pragma unroll
      for(int ni=0;ni<8;ni++){
        const float o=(f<NF)? (acc[mi][ni]+bb[nloc+ni]) : 0.f;
        hi[ni]=f2bf(o); lo[ni]=f2bf(o-ubf(hi[ni]));
      }
      uint4 ph, pl;
      ph.x=(unsigned)hi[0]|((unsigned)hi[1]<<16); ph.y=(unsigned)hi[2]|((unsigned)hi[3]<<16);
      ph.z=(unsigned)hi[4]|((unsigned)hi[5]<<16); ph.w=(unsigned)hi[6]|((unsigned)hi[7]<<16);
      pl.x=(unsigned)lo[0]|((unsigned)lo[1]<<16); pl.y=(unsigned)lo[2]|((unsigned)lo[3]<<16);
      pl.z=(unsigned)lo[4]|((unsigned)lo[5]<<16); pl.w=(unsigned)lo[6]|((unsigned)lo[7]<<16);
      *(uint4*)(Kh+(size_t)f*128+nloc)=ph;
      *(uint4*)(Kl+(size_t)f*128+nloc)=pl;
    }
  } else {
    #pragma unroll
    for(int ni=0;ni<8;ni++){
      const int d=nloc+ni;
      unsigned short hi[4], lo[4];
      #pragma unroll
      for(int mi=0;mi<4;mi++){
        const int f=f0+mloc+mi;
        const float o=(f<NF)? (acc[mi][ni]+bb[d]) : 0.f;
        hi[mi]=f2bf(o); lo[mi]=f2bf(o-ubf(hi[mi]));
      }
      *(uint2*)(Vth+(size_t)d*NFP+f0+mloc)=make_uint2((unsigned)hi[0]|((unsigned)hi[1]<<16),(unsigned)hi[2]|((unsigned)hi[3]<<16));
      *(uint2*)(Vtl+(size_t)d*NFP+f0+mloc)=make_uint2((unsigned)lo[0]|((unsigned)lo[1]<<16),(unsigned)lo[2]|((unsigned)lo[3]<<16));
    }
  }
}

// ---------------- q = h @ Wq + bq -> bf16 hi/lo ----------------
__global__ __launch_bounds__(128)
void qproj_kern(const float* __restrict__ h, const float* __restrict__ Wq,
                const float* __restrict__ bq,
                unsigned short* __restrict__ qh, unsigned short* __restrict__ ql){
  __shared__ float hs[128];
  const int v=blockIdx.x, c=threadIdx.x;
  hs[c]=h[(v<<7)+c];
  __syncthreads();
  float acc=bq[c];
  #pragma unroll 8
  for (int k=0;k<128;k++) acc=fmaf(hs[k],Wq[(k<<7)+c],acc);
  const unsigned short hi=f2bf(acc);
  qh[(v<<7)+c]=hi; ql[(v<<7)+c]=f2bf(acc-ubf(hi));
}

// ---------------- MFMA scores (main loop) ----------------
__global__ __launch_bounds__(256)
void scoresM_kern(const unsigned short* __restrict__ qh, const unsigned short* __restrict__ ql,
                  const unsigned short* __restrict__ Kh, const unsigned short* __restrict__ Kl,
                  unsigned short* __restrict__ Pb){
  const int t=threadIdx.x, w=t>>6, lane=t&63;
  const int v0=blockIdx.y*64;
  const int col=lane&31, kg=lane>>5;
  const int r0=v0+col;
  const size_t a0base=(size_t)r0*128, a1base=(size_t)(r0+32)*128;
  for (int ft=0; ft<4; ft++){
    const int fsub=blockIdx.x*512+(w+4*ft)*32;
    if (fsub>=NFP) break;
    const int f=fsub+col;
    const size_t bbase=(size_t)f*128;
    floatx16 acc0=fzero16(), acc1=fzero16();
    #pragma unroll
    for (int ks=0; ks<8; ks++){
      const int ko=ks*16+kg*8;
      short8 a0h=ld8(qh+a0base+ko), a0l=ld8(ql+a0base+ko);
      short8 a1h=ld8(qh+a1base+ko), a1l=ld8(ql+a1base+ko);
      short8 bh =ld8(Kh+bbase+ko),  bl =ld8(Kl+bbase+ko);
      acc0=MFMA32(a0h,bh,acc0,0,0,0);
      acc0=MFMA32(a0h,bl,acc0,0,0,0);
      acc0=MFMA32(a0l,bh,acc0,0,0,0);
      acc1=MFMA32(a1h,bh,acc1,0,0,0);
      acc1=MFMA32(a1h,bl,acc1,0,0,0);
      acc1=MFMA32(a1l,bh,acc1,0,0,0);
    }
    const bool inF=(f<NF);
    #pragma unroll
    for (int r=0;r<16;r++){
      const int rr=(r&3)+8*(r>>2)+4*kg;
      {
        const int row=v0+rr;
        const float s=acc0[r]*SCALE_QK;
        const float ep=inF? __expf(s):0.f;
        Pb[(size_t)row*NFP+f]=f2bf(ep);
      }
      {
        const int row=v0+32+rr;
        const float s=acc1[r]*SCALE_QK;
        const float ep=inF? __expf(s):0.f;
        Pb[(size_t)row*NFP+f]=f2bf(ep);
      }
    }
  }
}

// ---------------- MFMA PV (+ Z row-sums via ones-MFMA) ----------------
template<int SUMZ>
__global__ __launch_bounds__(256)
void pvM_kern(const unsigned short* __restrict__ Pb,
              const unsigned short* __restrict__ Vth, const unsigned short* __restrict__ Vtl,
              float* __restrict__ part, float* __restrict__ accg){
  __shared__ float Zs[64];
  const int t=threadIdx.x, w=t>>6, lane=t&63;
  const int slice=blockIdx.x, v0=blockIdx.y*64;
  const int col=lane&31, kg=lane>>5;
  const int d0=w*32;
  const int fbeg=slice*2048, fend=min(fbeg+2048,(int)NFP);
  if (SUMZ){ if (t<64) Zs[t]=0.f; __syncthreads(); }
  floatx16 acc0=fzero16(), acc1=fzero16(), z0=fzero16(), z1=fzero16();
  const short8 ones={(short)0x3F80,(short)0x3F80,(short)0x3F80,(short)0x3F80,
                     (short)0x3F80,(short)0x3F80,(short)0x3F80,(short)0x3F80};
  const unsigned short* pr0=Pb+(size_t)(v0+col)*NFP;
  const unsigned short* pr1=Pb+(size_t)(v0+32+col)*NFP;
  const unsigned short* vh =Vth+(size_t)(d0+col)*NFP;
  const unsigned short* vl =Vtl+(size_t)(d0+col)*NFP;
  for (int fc=fbeg; fc<fend; fc+=16){
    const int ko=fc+kg*8;
    short8 a0=ld8(pr0+ko), a1=ld8(pr1+ko);
    short8 bh=ld8(vh+ko),  bl=ld8(vl+ko);
    acc0=MFMA32(a0,bh,acc0,0,0,0);
    acc0=MFMA32(a0,bl,acc0,0,0,0);
    acc1=MFMA32(a1,bh,acc1,0,0,0);
    acc1=MFMA32(a1,bl,acc1,0,0,0);
    if (SUMZ && (((fc>>4)&3)==w)){
      z0=MFMA32(a0,ones,z0,0,0,0);
      z1=MFMA32(a1,ones,z1,0,0,0);
    }
  }
  const int d=d0+col;
  #pragma unroll
  for (int r=0;r<16;r++){
    const int rr=(r&3)+8*(r>>2)+4*kg;
    part[(((size_t)slice*NV+(v0+rr))<<7)+d]   =acc0[r];
    part[(((size_t)slice*NV+(v0+32+rr))<<7)+d]=acc1[r];
  }
  if (SUMZ){
    if (col==0){
      #pragma unroll
      for (int r=0;r<16;r++){
        const int rr=(r&3)+8*(r>>2)+4*kg;
        atomicAdd(&Zs[rr],z0[r]);
        atomicAdd(&Zs[32+rr],z1[r]);
      }
    }
    __syncthreads();
    if (t<64) atomicAdd(&accg[v0+t],Zs[t]);
  }
}

// ---------------- FINAL scores (SIMD fp32, runs once) ----------------
__global__ __launch_bounds__(256)
void scoresF_kern(const unsigned short* __restrict__ qh, const unsigned short* __restrict__ ql,
                  const unsigned short* __restrict__ Kh, const unsigned short* __restrict__ Kl,
                  const float* __restrict__ gum, unsigned short* __restrict__ Pb,
                  float* __restrict__ accg){
  __shared__ float As[32][68];
  __shared__ float Bs[32][132];
  __shared__ float Zs[64], Zls[64], Yps[64], Yls[64];
  const int t=threadIdx.x;
  const int f0=blockIdx.x*128;
  const int v0=blockIdx.y*64;
  float acc[4][8];
  #pragma unroll
  for(int i=0;i<4;i++){ for(int j=0;j<8;j++) acc[i][j]=0.f; }
  if (t<64){ Zs[t]=0.f; Zls[t]=0.f; Yps[t]=0.f; Yls[t]=0.f; }
  for (int kc=0;kc<128;kc+=32){
    { const int vloc=t>>2, koff=(t&3)*8;
      const size_t base=((size_t)(v0+vloc)<<7)+kc+koff;
      uint4 H=*(const uint4*)(qh+base), L=*(const uint4*)(ql+base);
      As[koff+0][vloc]=bflo(H.x)+bflo(L.x); As[koff+1][vloc]=bfhi(H.x)+bfhi(L.x);
      As[koff+2][vloc]=bflo(H.y)+bflo(L.y); As[koff+3][vloc]=bfhi(H.y)+bfhi(L.y);
      As[koff+4][vloc]=bflo(H.z)+bflo(L.z); As[koff+5][vloc]=bfhi(H.z)+bfhi(L.z);
      As[koff+6][vloc]=bflo(H.w)+bflo(L.w); As[koff+7][vloc]=bfhi(H.w)+bfhi(L.w); }
    { const int floc=t>>1, koff=(t&1)*16; const int f=f0+floc;
      const size_t base=((size_t)f<<7)+kc+koff;
      uint4 H0=*(const uint4*)(Kh+base), H1=*(const uint4*)(Kh+base+8);
      uint4 L0=*(const uint4*)(Kl+base), L1=*(const uint4*)(Kl+base+8);
      Bs[koff+0][floc]=bflo(H0.x)+bflo(L0.x); Bs[koff+1][floc]=bfhi(H0.x)+bfhi(L0.x);
      Bs[koff+2][floc]=bflo(H0.y)+bflo(L0.y); Bs[koff+3][floc]=bfhi(H0.y)+bfhi(L0.y);
      Bs[koff+4][floc]=bflo(H0.z)+bflo(L0.z); Bs[koff+5][floc]=bfhi(H0.z)+bfhi(L0.z);
      Bs[koff+6][floc]=bflo(H0.w)+bflo(L0.w); Bs[koff+7][floc]=bfhi(H0.w)+bfhi(L0.w);
      Bs[koff+8][floc]=bflo(H1.x)+bflo(L1.x); Bs[koff+9][floc]=bfhi(H1.x)+bfhi(L1.x);
      Bs[koff+10][floc]=bflo(H1.y)+bflo(L1.y); Bs[koff+11][floc]=bfhi(H1.y)+bfhi(L1.y);
      Bs[koff+12][floc]=bflo(H1.z)+bflo(L1.z); Bs[koff+13][floc]=bfhi(H1.z)+bfhi(L1.z);
      Bs[koff+14][floc]=bflo(H1.w)+bflo(L1.w); Bs[koff+15][floc]=bfhi(H1.w)+bfhi(L1.w); }
    __syncthreads();
    const int mloc=(t&15)*4, nloc=(t>>4)*8;
    #pragma unroll
    for (int kk=0;kk<32;kk++){
      const float4 a=*(const float4*)&As[kk][mloc];
      const float4 b0=*(const float4*)&Bs[kk][nloc];
      const float4 b1=*(const float4*)&Bs[kk][nloc+4];
      const float am[4]={a.x,a.y,a.z,a.w};
      const float bn[8]={b0.x,b0.y,b0.z,b0.w,b1.x,b1.y,b1.z,b1.w};
      #pragma unroll
      for(int mi=0;mi<4;mi++){
        #pragma unroll
        for(int ni=0;ni<8;ni++) acc[mi][ni]=fmaf(am[mi],bn[ni],acc[mi][ni]);
      }
    }
    __syncthreads();
  }
  const int mloc=(t&15)*4, nloc=(t>>4)*8;
  #pragma unroll
  for(int mi=0;mi<4;mi++){
    const int v=v0+mloc+mi;
    float zp=0.f, zl=0.f, yp=0.f, yl=0.f;
    float uu[8];
    { const int fbase=f0+nloc;
      if (fbase+8<=NF){
        const float* gsrc=gum+(size_t)v*NF+fbase;
        float4 g0=*(const float4*)gsrc, g1=*(const float4*)(gsrc+4);
        uu[0]=g0.x;uu[1]=g0.y;uu[2]=g0.z;uu[3]=g0.w;uu[4]=g1.x;uu[5]=g1.y;uu[6]=g1.z;uu[7]=g1.w;
      } else {
        for(int i=0;i<8;i++){ int f=fbase+i; uu[i]=(f<NF)? gum[(size_t)v*NF+f] : 0.5f; }
      } }
    unsigned short pr[8];
    #pragma unroll
    for(int ni=0;ni<8;ni++){
      const int f=f0+nloc+ni;
      const float s=acc[mi][ni]*SCALE_QK;
      float pv_=0.f;
      if (f<NF){
        const float ep=__expf(s);
        const float g=-__logf(-__logf(uu[ni]));
        const float el=__expf(2.0f*(s+g));
        pv_=el; zl+=el; yl+=el*s; zp+=ep; yp+=ep*s;
      }
      pr[ni]=f2bf(pv_);
    }
    uint4 pk;
    pk.x=(unsigned)pr[0]|((unsigned)pr[1]<<16);
    pk.y=(unsigned)pr[2]|((unsigned)pr[3]<<16);
    pk.z=(unsigned)pr[4]|((unsigned)pr[5]<<16);
    pk.w=(unsigned)pr[6]|((unsigned)pr[7]<<16);
    *(uint4*)(Pb+(size_t)v*NFP+f0+nloc)=pk;
    atomicAdd(&Zs[mloc+mi],zp);
    atomicAdd(&Zls[mloc+mi],zl); atomicAdd(&Yps[mloc+mi],yp); atomicAdd(&Yls[mloc+mi],yl);
  }
  __syncthreads();
  if (t<64){
    atomicAdd(&accg[v0+t],Zs[t]);
    atomicAdd(&accg[1024+v0+t],Zls[t]);
    atomicAdd(&accg[2048+v0+t],Yps[t]);
    atomicAdd(&accg[3072+v0+t],Yls[t]);
  }
}

// ---------------- main-loop gate update ----------------
__global__ __launch_bounds__(256)
void gate_kern(float* __restrict__ h, const float* __restrict__ part, const float* __restrict__ Z,
               const float* __restrict__ Wm1, const float* __restrict__ bm1,
               const float* __restrict__ Wm2, const float* __restrict__ bm2){
  const int t=threadIdx.x, w=t>>6, lane=t&63;
  const int v=(blockIdx.x<<2)+w;
  const float h0=h[(v<<7)+lane], h1=h[(v<<7)+64+lane];
  const float zr=1.0f/Z[v];
  float c0=0.f,c1=0.f;
  for (int s=0;s<NSLICE;s++){
    c0+=part[(((size_t)s*NV+v)<<7)+lane];
    c1+=part[(((size_t)s*NV+v)<<7)+64+lane];
  }
  c0*=zr; c1*=zr;
  float y0=bm1[lane], y1=bm1[64+lane];
  for (int k=0;k<64;k++){ const float a=__shfl(h0,k); y0=fmaf(a,Wm1[(k<<7)+lane],y0);      y1=fmaf(a,Wm1[(k<<7)+64+lane],y1); }
  for (int k=0;k<64;k++){ const float a=__shfl(h1,k); y0=fmaf(a,Wm1[((64+k)<<7)+lane],y0); y1=fmaf(a,Wm1[((64+k)<<7)+64+lane],y1); }
  for (int k=0;k<64;k++){ const float a=__shfl(c0,k); y0=fmaf(a,Wm1[((128+k)<<7)+lane],y0);y1=fmaf(a,Wm1[((128+k)<<7)+64+lane],y1); }
  for (int k=0;k<64;k++){ const float a=__shfl(c1,k); y0=fmaf(a,Wm1[((192+k)<<7)+lane],y0);y1=fmaf(a,Wm1[((192+k)<<7)+64+lane],y1); }
  y0=geluf(y0); y1=geluf(y1);
  float z0=bm2[lane], z1=bm2[64+lane];
  for (int k=0;k<64;k++){ const float a=__shfl(y0,k); z0=fmaf(a,Wm2[(k<<7)+lane],z0);      z1=fmaf(a,Wm2[(k<<7)+64+lane],z1); }
  for (int k=0;k<64;k++){ const float a=__shfl(y1,k); z0=fmaf(a,Wm2[((64+k)<<7)+lane],z0); z1=fmaf(a,Wm2[((64+k)<<7)+64+lane],z1); }
  const float g0=sigmf(z0), g1=sigmf(z1);
  h[(v<<7)+lane]   = fmaf(g0,c0-h0,h0);
  h[(v<<7)+64+lane]= fmaf(g1,c1-h1,h1);
}

// ---------------- cooc scan: 8 blocks x 1024 thr, fused data+flag sync ----------------
// Block owns 128 vars (wave owns 8). Per atom:
//  P0: stage X (h -> bf16 hi/lo, swizzle (row&15)<<3) | poll 8 flags >= a+1 |
//  P1: avgs = sum of 8 slots / cnt |
//  P2: ypart (avg @ Wc1_bot, VALU) + Y-GEMM (16 waves, 4x4 tiles, 24 MFMA) |
//  P3: Y = gelu(accY + yav + bc1) -> LDS |  P4: Z-GEMM; G -> LDS (over X) |
//  P5: h update + seed partial for a+1 |  P6: publish slot[(a+1)%3] + drain + flag=a+2
// Seeds: plain relaxed stores to per-block slot, 3-deep rotation (no atomics, no zeroing).
// Flag ordering: __syncthreads drains vmcnt before the flag store (validated pattern).
__global__ __launch_bounds__(1024,1)
void cooc_kern(float* __restrict__ h, const int* __restrict__ cm, const float* __restrict__ cntf,
               const float* __restrict__ Wc1, const float* __restrict__ bc1,
               const float* __restrict__ Wc2, const float* __restrict__ bc2,
               float* __restrict__ slots, unsigned* __restrict__ flags){
  __shared__ unsigned short XBUF[2*128*128];   // Xh | Xl ; aliased by Gs (fp32 128x128) in P4..P5
  __shared__ unsigned short Yh[128*128], Yl[128*128];
  __shared__ float ypart2[8*128];
  __shared__ float avgs[128], seedb[128], bc1s[128], bc2s[128], cnts[64];
  unsigned short* Xh=XBUF;
  unsigned short* Xl=XBUF+16384;
  float* Gs=(float*)XBUF;
  const int t=threadIdx.x, w=t>>6, lane=t&63;
  const int bid=blockIdx.x;
  const int col=lane&31, kg=lane>>5;
  const int rt=w&3, ct=w>>2, n0=ct*32;
  const int v0=(bid<<7)+(w<<3);          // first of this wave's 8 vars

  // ---- one-time staging ----
  if (t<128){ bc1s[t]=bc1[t]; bc2s[t]=bc2[t]; seedb[t]=0.f; }
  else if (t<192) cnts[t-128]=cntf[t-128];
  // register B-fragments: Wc1_top cols [n0,n0+32) and Wc2 cols [n0,n0+32)
  short8 B1h[8],B1l[8],B2h[8],B2l[8];
  #pragma unroll
  for (int ks=0;ks<8;ks++){
    #pragma unroll
    for (int j=0;j<8;j++){
      const int k=ks*16+kg*8+j;
      const float x1=Wc1[k*128+n0+col];
      const float x2=Wc2[k*128+n0+col];
      const unsigned short h1v=f2bf(x1), h2v=f2bf(x2);
      B1h[ks][j]=(short)h1v; B1l[ks][j]=(short)f2bf(x1-ubf(h1v));
      B2h[ks][j]=(short)h2v; B2l[ks][j]=(short)f2bf(x2-ubf(h2v));
    }
  }
  // membership masks + h (8 vars per wave; dims lane and 64+lane)
  unsigned long long amask[8];
  float h0[8], h1[8];
  #pragma unroll
  for (int j=0;j<8;j++){
    amask[j]=__ballot(cm[lane*NV+(v0+j)]!=0);
    h0[j]=h[((v0+j)<<7)+lane];
    h1[j]=h[((v0+j)<<7)+64+lane];
  }
  __syncthreads();
  // ---- seed atom 0 ----
  { float s0=0.f,s1=0.f;
    #pragma unroll
    for (int j=0;j<8;j++) if (amask[j]&1ull){ s0+=h0[j]; s1+=h1[j]; }
    atomicAdd(&seedb[lane],s0); atomicAdd(&seedb[64+lane],s1); }
  __syncthreads();
  if (t<128){ float s=seedb[t]; seedb[t]=0.f;
    __hip_atomic_store(&slots[(bid<<7)+t], s, __ATOMIC_RELAXED, __HIP_MEMORY_SCOPE_AGENT); }
  __syncthreads();   // drain slot stores
  if (t==0) __hip_atomic_store(&flags[bid<<5], 1u, __ATOMIC_RELAXED, __HIP_MEMORY_SCOPE_AGENT);

  for (int a=0;a<NA;a++){
    const float cf=cnts[a];
    // ---- P0: stage X ----
    #pragma unroll
    for (int j=0;j<8;j++){
      const int row=(w<<3)+j;
      const int sw=(row&15)<<3;
      const unsigned short h0h=f2bf(h0[j]), h1h=f2bf(h1[j]);
      const unsigned short h0l=f2bf(h0[j]-ubf(h0h)), h1l=f2bf(h1[j]-ubf(h1h));
      Xh[(row<<7)+(lane^sw)]=h0h;      Xl[(row<<7)+(lane^sw)]=h0l;
      Xh[(row<<7)+((64+lane)^sw)]=h1h; Xl[(row<<7)+((64+lane)^sw)]=h1l;
    }
    __syncthreads();   // also drains previous flag store
    // ---- P0b: poll 8 producer flags ----
    if (t<8){
      while (__hip_atomic_load(&flags[t<<5], __ATOMIC_RELAXED, __HIP_MEMORY_SCOPE_AGENT) < (unsigned)(a+1))
        __builtin_amdgcn_s_sleep(1);
    }
    __syncthreads();
    // ---- P1: avgs ----
    if (t<128){
      float s=0.f;
      const int e=(a%3)<<10;
      #pragma unroll
      for (int sp=0;sp<8;sp++)
        s+=__hip_atomic_load(&slots[e+(sp<<7)+t], __ATOMIC_RELAXED, __HIP_MEMORY_SCOPE_AGENT);
      avgs[t]=s/fmaxf(cf,1.0f);
    }
    __syncthreads();
    // ---- P2: ypart (all threads) + Y-GEMM (all 16 waves) ----
    { const int seg=t>>7, c2=t&127, kb=seg<<4;
      float sacc=0.f;
      #pragma unroll
      for (int j=0;j<16;j++) sacc=fmaf(avgs[kb+j],Wc1[(128+kb+j)*128+c2],sacc);
      ypart2[(seg<<7)+c2]=sacc; }
    floatx16 accY=fzero16();
    { const int arow=(rt<<5)+col;
      const int sw=(arow&15)<<3;
      #pragma unroll
      for (int ks=0;ks<8;ks++){
        const int ko=(ks*16+kg*8)^sw;
        short8 ah=ld8(&Xh[(arow<<7)+ko]), al=ld8(&Xl[(arow<<7)+ko]);
        accY=MFMA32(ah,B1h[ks],accY,0,0,0);
        accY=MFMA32(al,B1h[ks],accY,0,0,0);
        accY=MFMA32(ah,B1l[ks],accY,0,0,0);
      } }
    __syncthreads();
    // ---- P3: Y = gelu(accY + yav) -> Yh/Yl ----
    { const int c=n0+col;
      float yav=bc1s[c];
      #pragma unroll
      for (int seg=0;seg<8;seg++) yav+=ypart2[(seg<<7)+c];
      #pragma unroll
      for (int r=0;r<16;r++){
        const int rr=(r&3)+8*(r>>2)+4*kg;
        const int row=(rt<<5)+rr;
        const float yv=geluf(accY[r]+yav);
        const unsigned short yh=f2bf(yv);
        const unsigned short yl=f2bf(yv-ubf(yh));
        const int wi=(row<<7)+(c^((row&15)<<3));
        Yh[wi]=yh; Yl[wi]=yl;
      } }
    __syncthreads();
    // ---- P4: Z-GEMM; G -> Gs (overwrites X region) ----
    { floatx16 accZ=fzero16();
      const int arow=(rt<<5)+col;
      const int sw=(arow&15)<<3;
      #pragma unroll
      for (int ks=0;ks<8;ks++){
        const int ko=(ks*16+kg*8)^sw;
        short8 ah=ld8(&Yh[(arow<<7)+ko]), al=ld8(&Yl[(arow<<7)+ko]);
        accZ=MFMA32(ah,B2h[ks],accZ,0,0,0);
        accZ=MFMA32(al,B2h[ks],accZ,0,0,0);
        accZ=MFMA32(ah,B2l[ks],accZ,0,0,0);
      }
      const int c=n0+col;
      const float b2=bc2s[c];
      #pragma unroll
      for (int r=0;r<16;r++){
        const int rr=(r&3)+8*(r>>2)+4*kg;
        const int row=(rt<<5)+rr;
        Gs[(row<<7)+c]=sigmf(accZ[r]+b2);
      } }
    __syncthreads();
    // ---- P5: h update + seed partial for a+1 ----
    { const float av0=avgs[lane], av1=avgs[64+lane];
      const bool cok=(cf>=2.0f);
      float s0=0.f,s1=0.f;
      #pragma unroll
      for (int j=0;j<8;j++){
        const int row=(w<<3)+j;
        if (cok && ((amask[j]>>a)&1ull)){
          const float g0=Gs[(row<<7)+lane], g1=Gs[(row<<7)+64+lane];
          h0[j]=fmaf(g0,av0-h0[j],h0[j]);
          h1[j]=fmaf(g1,av1-h1[j],h1[j]);
        }
        if (a<NA-1 && ((amask[j]>>(a+1))&1ull)){ s0+=h0[j]; s1+=h1[j]; }
      }
      if (a<NA-1){ atomicAdd(&seedb[lane],s0); atomicAdd(&seedb[64+lane],s1); } }
    __syncthreads();
    // ---- P6: publish seed for a+1 ----
    if (a<NA-1){
      if (t<128){
        const float s=seedb[t]; seedb[t]=0.f;
        __hip_atomic_store(&slots[(((a+1)%3)<<10)+(bid<<7)+t], s, __ATOMIC_RELAXED, __HIP_MEMORY_SCOPE_AGENT);
      }
      __syncthreads();   // drain slot stores before flag
      if (t==0) __hip_atomic_store(&flags[bid<<5], (unsigned)(a+2), __ATOMIC_RELAXED, __HIP_MEMORY_SCOPE_AGENT);
    }
  }
  #pragma unroll
  for (int j=0;j<8;j++){
    h[((v0+j)<<7)+lane]   =h0[j];
    h[((v0+j)<<7)+64+lane]=h1[j];
  }
}

// ---------------- final write-out ----------------
__global__ __launch_bounds__(256)
void writeout_kern(const float* __restrict__ accg, const float* __restrict__ part,
                   float* __restrict__ out){
  const int b=blockIdx.x, t=threadIdx.x;
  const int v0=b*16;
  for (int i=t;i<16*128;i+=256){
    const int v=v0+(i>>7), d=i&127;
    float s=0.f;
    for (int sl=0;sl<NSLICE;sl++) s+=part[(((size_t)sl*NV+v)<<7)+d];
    out[1+((size_t)v<<7)+d]=s/accg[1024+v];
  }
  __shared__ float es[16], hsv[16];
  if (t<16){
    const int v=v0+t;
    const float Zp=accg[v], Zl=accg[1024+v], Yp=accg[2048+v], Yl=accg[3072+v];
    es[t]=-Yl/Zl;
    hsv[t]=-(Yp/Zp-logf(Zp));
  }
  __syncthreads();
  if (t==0){
    float a=0.f,c=0.f;
    for(int i=0;i<16;i++){ a+=es[i]; c+=hsv[i]; }
    atomicAdd(&out[0],a);
    atomicAdd(&out[1+(size_t)NV*128],c);
  }
}

// ---------------- host ----------------
extern "C" void kernel_launch(void* const* d_in, const int* in_sizes, int n_in,
                              void* d_out, int out_size, void* d_ws, size_t ws_size,
                              hipStream_t stream){
  (void)in_sizes; (void)n_in; (void)ws_size;
  const float* fe =(const float*)d_in[0];
  const float* vi =(const float*)d_in[1];
  const int*   cm =(const int*)  d_in[2];
  const float* gum=(const float*)d_in[3];
  const float* Wq =(const float*)d_in[4];  const float* bq =(const float*)d_in[5];
  const float* Wk =(const float*)d_in[6];  const float* bk =(const float*)d_in[7];
  const float* Wv =(const float*)d_in[8];  const float* bv =(const float*)d_in[9];
  const float* Wm1=(const float*)d_in[10]; const float* bm1=(const float*)d_in[11];
  const float* Wm2=(const float*)d_in[12]; const float* bm2=(const float*)d_in[13];
  const float* Wc1=(const float*)d_in[14]; const float* bc1=(const float*)d_in[15];
  const float* Wc2=(const float*)d_in[16]; const float* bc2=(const float*)d_in[17];
  float* out=(float*)d_out;
  char* w8=(char*)d_ws;
  unsigned short* Kh =(unsigned short*)(w8+OFF_KH);
  unsigned short* Kl =(unsigned short*)(w8+OFF_KL);
  unsigned short* Vth=(unsigned short*)(w8+OFF_VTH);
  unsigned short* Vtl=(unsigned short*)(w8+OFF_VTL);
  unsigned short* Pb =(unsigned short*)(w8+OFF_P);
  float* hb  =(float*)(w8+OFF_H);
  unsigned short* qhb=(unsigned short*)(w8+OFF_QH);
  unsigned short* qlb=(unsigned short*)(w8+OFF_QL);
  float* part=(float*)(w8+OFF_PART);
  float* accb=(float*)(w8+OFF_ACC);
  float* slots=accb+4096;                 // 3*1024 floats (seed slot rotation)
  float* cntf=(float*)(w8+OFF_CNT);
  unsigned* flags=(unsigned*)(w8+OFF_P);  // overlays dead-at-cooc-time P head

  hipMemsetAsync(out,0,(size_t)out_size*4,stream);
  hipMemcpyAsync(hb,vi,(size_t)NV*128*4,hipMemcpyDeviceToDevice,stream);
  cnt_kern<<<NA,256,0,stream>>>(cm,cntf);
  kvproj_kern<<<dim3(NFP/64,2),256,0,stream>>>(fe,Wk,bk,Wv,bv,Kh,Kl,Vth,Vtl);

  for (int it=0; it<3; it++){
    hipMemsetAsync(accb,0,28672,stream);
    qproj_kern<<<NV,128,0,stream>>>(hb,Wq,bq,qhb,qlb);
    scoresM_kern<<<dim3(98,16),256,0,stream>>>(qhb,qlb,Kh,Kl,Pb);
    pvM_kern<1><<<dim3(NSLICE,16),256,0,stream>>>(Pb,Vth,Vtl,part,accb);
    gate_kern<<<NV/4,256,0,stream>>>(hb,part,accb,Wm1,bm1,Wm2,bm2);
    hipMemsetAsync(flags,0,2304,stream);
    cooc_kern<<<8,1024,0,stream>>>(hb,cm,cntf,Wc1,bc1,Wc2,bc2,slots,flags);
  }

  hipMemsetAsync(accb,0,28672,stream);
  qproj_kern<<<NV,128,0,stream>>>(hb,Wq,bq,qhb,qlb);
  scoresF_kern<<<dim3(NFP/128,16),256,0,stream>>>(qhb,qlb,Kh,Kl,gum,Pb,accb);
  pvM_kern<0><<<dim3(NSLICE,16),256,0,stream>>>(Pb,Vth,Vtl,part,accb);
  writeout_kern<<<64,256,0,stream>>>(accb,part,out);
}